// Round 1
// baseline (47.986 us; speedup 1.0000x reference)
//
#include <hip/hip_runtime.h>
#include <hip/hip_bf16.h>

#define TB 256
#define BDIM 256
#define NDIM 512
#define CDIM 1000
#define RDIM 64
#define BK 64

typedef __attribute__((ext_vector_type(4))) float f32x4;
typedef __attribute__((ext_vector_type(8))) short bf16x8;

__device__ __forceinline__ uint32_t pk2(float lo, float hi) {
    unsigned short l = __builtin_bit_cast(unsigned short, __float2bfloat16(lo));
    unsigned short h = __builtin_bit_cast(unsigned short, __float2bfloat16(hi));
    return ((uint32_t)h << 16) | (uint32_t)l;
}

__global__ __launch_bounds__(256, 2)
void Mahalanobis_72834055405642_kernel(const float* __restrict__ x,
                                       const float* __restrict__ w,
                                       const float* __restrict__ bias,
                                       float* __restrict__ out)
{
    // bf16 tiles, XOR-swizzled: byte_off ^= (row&7)<<4
    __shared__ alignas(16) char lds_x[BDIM * BK * 2];   // [256][64] bf16
    __shared__ alignas(16) char lds_w[128 * BK * 2];    // [128][64] bf16
    __shared__ alignas(16) float bias_lds[2 * NDIM];    // bias rows c0, c0+1
    __shared__ float sb_lds[128];                       // Wb per tile col

    const int tid  = threadIdx.x;
    const int lane = tid & 63;
    const int wv   = tid >> 6;
    const int l15  = lane & 15;
    const int lhi  = lane >> 4;
    const int c0   = blockIdx.x * 2;

    // stage bias rows c0, c0+1 (1024 floats = 256 float4)
    {
        const float4 bv = reinterpret_cast<const float4*>(bias + (size_t)c0 * NDIM)[tid];
        reinterpret_cast<float4*>(bias_lds)[tid] = bv;
    }

    f32x4 acc[4][8];
    #pragma unroll
    for (int m = 0; m < 4; ++m)
        #pragma unroll
        for (int n = 0; n < 8; ++n)
            acc[m][n] = (f32x4){0.f, 0.f, 0.f, 0.f};

    const int jrow = tid >> 1;      // W-tile row 0..127 (= cl*64 + r)
    const int jh   = tid & 1;       // 32-col half
    const int cl   = jrow >> 6;
    const float* wbase  = w + (size_t)(c0 + cl) * (RDIM * NDIM)
                            + (size_t)(jrow & 63) * NDIM + jh * 32;
    const float* blbase = bias_lds + cl * NDIM + jh * 32;
    const int xrow = tid >> 2;      // 0..63
    const int xq   = tid & 3;

    float sbp = 0.f;

    __syncthreads();   // bias visible before Sb accumulation

    for (int kk = 0; kk < NDIM; kk += BK) {
        // ---- stage x tile: rows p*64+xrow, cols kk + xq*16 .. +15 (L2-resident)
        #pragma unroll
        for (int p = 0; p < 4; ++p) {
            const int r = p * 64 + xrow;
            const float4* src = reinterpret_cast<const float4*>(
                x + (size_t)r * NDIM + kk + xq * 16);
            float4 v0 = src[0], v1 = src[1], v2 = src[2], v3 = src[3];
            uint4 pa = {pk2(v0.x, v0.y), pk2(v0.z, v0.w), pk2(v1.x, v1.y), pk2(v1.z, v1.w)};
            uint4 pb = {pk2(v2.x, v2.y), pk2(v2.z, v2.w), pk2(v3.x, v3.y), pk2(v3.z, v3.w)};
            const int sw = (r & 7) << 4;
            char* rowp = lds_x + r * (BK * 2);
            *reinterpret_cast<uint4*>(rowp + ((xq * 32) ^ sw))      = pa;
            *reinterpret_cast<uint4*>(rowp + ((xq * 32 + 16) ^ sw)) = pb;
        }
        // ---- stage W tile (HBM stream) + fused fp32 Sb partial
        {
            const float4* src = reinterpret_cast<const float4*>(wbase + kk);
            const float4* bl  = reinterpret_cast<const float4*>(blbase + kk);
            char* rowp = lds_w + jrow * (BK * 2);
            const int sw = (jrow & 7) << 4;
            #pragma unroll
            for (int i2 = 0; i2 < 4; ++i2) {
                float4 va = src[i2 * 2];
                float4 vb = src[i2 * 2 + 1];
                float4 ba = bl[i2 * 2];
                float4 bb = bl[i2 * 2 + 1];
                sbp += va.x * ba.x + va.y * ba.y + va.z * ba.z + va.w * ba.w
                     + vb.x * bb.x + vb.y * bb.y + vb.z * bb.z + vb.w * bb.w;
                uint4 pkv = {pk2(va.x, va.y), pk2(va.z, va.w),
                             pk2(vb.x, vb.y), pk2(vb.z, vb.w)};
                *reinterpret_cast<uint4*>(rowp + ((jh * 64 + i2 * 16) ^ sw)) = pkv;
            }
        }
        __syncthreads();
        // ---- MFMA: 2 k-steps of 32, frags via swizzled ds_read_b128
        #pragma unroll
        for (int ks = 0; ks < 2; ++ks) {
            bf16x8 af[4];
            bf16x8 bfr[8];
            const int swr = (l15 & 7) << 4;
            #pragma unroll
            for (int m = 0; m < 4; ++m) {
                const int row = wv * 64 + m * 16 + l15;
                af[m] = *reinterpret_cast<const bf16x8*>(
                    lds_x + row * (BK * 2) + ((ks * 64 + lhi * 16) ^ swr));
            }
            #pragma unroll
            for (int n = 0; n < 8; ++n) {
                const int row = n * 16 + l15;
                bfr[n] = *reinterpret_cast<const bf16x8*>(
                    lds_w + row * (BK * 2) + ((ks * 64 + lhi * 16) ^ swr));
            }
            #pragma unroll
            for (int m = 0; m < 4; ++m)
                #pragma unroll
                for (int n = 0; n < 8; ++n)
                    acc[m][n] = __builtin_amdgcn_mfma_f32_16x16x32_bf16(
                        af[m], bfr[n], acc[m][n], 0, 0, 0);
        }
        __syncthreads();
    }

    // ---- Sb: reduce n-half pairs (tid, tid^1), publish to LDS
    sbp += __shfl_xor(sbp, 1);
    if (jh == 0) sb_lds[jrow] = sbp;
    __syncthreads();

    float sb[8];
    #pragma unroll
    for (int n = 0; n < 8; ++n) sb[n] = sb_lds[n * 16 + l15];

    // ---- epilogue: out[b,c] = sum_r (S - Sb)^2 ; 16-lane butterfly over col residues
    #pragma unroll
    for (int m = 0; m < 4; ++m) {
        #pragma unroll
        for (int rg = 0; rg < 4; ++rg) {
            float p0 = 0.f, p1 = 0.f;
            #pragma unroll
            for (int n = 0; n < 4; ++n) {
                const float d0 = acc[m][n][rg]     - sb[n];
                const float d1 = acc[m][n + 4][rg] - sb[n + 4];
                p0 += d0 * d0;
                p1 += d1 * d1;
            }
            #pragma unroll
            for (int s = 1; s < 16; s <<= 1) {
                p0 += __shfl_xor(p0, s);
                p1 += __shfl_xor(p1, s);
            }
            if (l15 == 0) {
                const int b = wv * 64 + m * 16 + lhi * 4 + rg;
                float2 o2 = {p0, p1};
                *reinterpret_cast<float2*>(out + (size_t)b * CDIM + c0) = o2;
            }
        }
    }
}

extern "C" void kernel_launch(void* const* d_in, const int* in_sizes, int n_in,
                              void* d_out, int out_size, void* d_ws, size_t ws_size,
                              hipStream_t stream) {
    const float* x    = (const float*)d_in[0];
    const float* w    = (const float*)d_in[1];
    const float* bias = (const float*)d_in[2];
    float* out = (float*)d_out;
    dim3 grid(CDIM / 2);   // one block per 2 classes
    dim3 block(TB);
    hipLaunchKernelGGL(Mahalanobis_72834055405642_kernel, grid, block, 0, stream,
                       x, w, bias, out);
}